// Round 1
// baseline (289.836 us; speedup 1.0000x reference)
//
#include <hip/hip_runtime.h>
#include <hip/hip_bf16.h>

typedef __attribute__((ext_vector_type(8))) short short8;  // 8 bf16 (4 VGPRs)
typedef __attribute__((ext_vector_type(4))) float f32x4;   // MFMA acc

// ws layout (bytes):
//   [0,     16384)             Weff fp32 [16][16][16]  (p,d,e)
//   [16384, 16448)             beff fp32 [16]
//   [16448, 16448 + N*64)      Xb  bf16 [N][32]      (e padded 16->32, zeros)
// All sub-offsets 16B-aligned for dwordx4 access.

__global__ void k_prep(const float* __restrict__ nodes,
                       const float* __restrict__ W_bil,
                       const float* __restrict__ b_bil,
                       const float* __restrict__ W2,
                       const float* __restrict__ b2,
                       const float* __restrict__ W3,
                       const float* __restrict__ b3,
                       float* __restrict__ Weff,
                       float* __restrict__ beff,
                       __hip_bfloat16* __restrict__ Xb,
                       int N)
{
    const int p = blockIdx.x;   // 16 blocks, one output channel each
    const int t = threadIdx.x;  // 256 threads

    __shared__ float wc[16];    // Wc[p][k] = sum_o W3[p,o] W2[o,k]
    if (t < 16) {
        float s = 0.f;
        #pragma unroll
        for (int o = 0; o < 16; ++o) s += W3[p * 16 + o] * W2[o * 16 + t];
        wc[t] = s;
    }
    __syncthreads();

    {   // Weff[p][d][e] = sum_k Wc[p,k] * W_bil[k,d,e]
        const int d = t >> 4, e = t & 15;
        float s = 0.f;
        #pragma unroll
        for (int k = 0; k < 16; ++k) s += wc[k] * W_bil[(k * 16 + d) * 16 + e];
        Weff[(p * 16 + d) * 16 + e] = s;
    }

    if (p == 0 && t < 16) {  // beff[t] = Wc[t,:]@b_bil + W3[t,:]@b2 + b3[t]
        float acc = b3[t];
        #pragma unroll
        for (int o = 0; o < 16; ++o) acc += W3[t * 16 + o] * b2[o];
        #pragma unroll
        for (int k = 0; k < 16; ++k) {
            float wck = 0.f;
            #pragma unroll
            for (int o = 0; o < 16; ++o) wck += W3[t * 16 + o] * W2[o * 16 + k];
            acc += wck * b_bil[k];
        }
        beff[t] = acc;
    }

    {   // Xb: one node row per thread (16 blocks * 256 = N), K-padded to 32
        const int n = p * 256 + t;
        if (n < N) {
            const float* src = nodes + (size_t)n * 16;
            __hip_bfloat16* dst = Xb + (size_t)n * 32;
            #pragma unroll
            for (int e = 0; e < 16; ++e) dst[e] = __float2bfloat16(src[e]);
            #pragma unroll
            for (int e = 16; e < 32; ++e) dst[e] = __float2bfloat16(0.f);
        }
    }
}

// Per block: one (b, i).
// Prologue: U_i[p][e] = sum_d x[i,d]*Weff[p,d,e] computed into LDS (bf16, e pad 32).
// Main: D[p][j] tile = MFMA(A = U_i [p][e], B = Xb [e][j]).
// C/D layout (m89-verified): col = lane&15 (=j), row = (lane>>4)*4 + reg (=p)
// -> each lane's 4 accs are 4 consecutive channels of one output row: 16B store.
__global__ __launch_bounds__(256) void k_main(
    const float* __restrict__ nodes,         // [N][16] fp32
    const float* __restrict__ Weff,          // [16][16][16] fp32 (p,d,e)
    const __hip_bfloat16* __restrict__ Xb,   // [N][32] bf16
    const float* __restrict__ beff,          // [16]
    float* __restrict__ out,                 // [B*M*(M-1)][16] fp32
    int M)
{
    const int blk  = blockIdx.x;        // == b*M + il == global node index i
    const int il   = blk % M;
    const int bM   = blk - il;          // b*M
    const int t    = threadIdx.x;

    // ---- fused U_i: 256 threads = 16p x 16e, one element each ----
    __shared__ float xr[16];
    __shared__ __hip_bfloat16 Us[16 * 32];   // [p][e pad 32]
    if (t < 16) xr[t] = nodes[(size_t)blk * 16 + t];
    __syncthreads();
    {
        const int p = t >> 4, e = t & 15;
        float s = 0.f;
        #pragma unroll
        for (int d = 0; d < 16; ++d) s += xr[d] * Weff[(p * 16 + d) * 16 + e];
        Us[p * 32 + e]      = __float2bfloat16(s);
        Us[p * 32 + 16 + e] = __float2bfloat16(0.f);  // K zero-pad
    }
    __syncthreads();

    const int w    = t >> 6;            // wave 0..3
    const int lane = t & 63;
    const int q    = lane >> 4;         // quad
    const int r16  = lane & 15;

    // A-frag: A[m=lane&15][k=quad*8+j] = U[i][p=r16][e=q*8..+7] (contiguous 16B)
    const short8 a = *reinterpret_cast<const short8*>(
        reinterpret_cast<const unsigned short*>(Us) + r16 * 32 + q * 8);

    // Acc init with beff: lane reg r holds D[p=q*4+r][*]
    f32x4 cinit;
    {
        const float4 bv = *reinterpret_cast<const float4*>(beff + q * 4);
        cinit = f32x4{bv.x, bv.y, bv.z, bv.w};
    }

    const unsigned short* Xu = reinterpret_cast<const unsigned short*>(Xb);
    const size_t xbase = (size_t)bM * 32;
    float* outb = out + (size_t)blk * (M - 1) * 16;

    const int ntiles = M >> 4;          // 64
    #pragma unroll 4
    for (int jt = w; jt < ntiles; jt += 4) {
        const int j = jt * 16 + r16;    // this lane's output column (node j)
        // B-frag: B[k=quad*8+i][n=lane&15] = Xb[bM+j][e=q*8..+7]
        const short8 bfr = *reinterpret_cast<const short8*>(
            Xu + xbase + (size_t)j * 32 + q * 8);
        f32x4 acc = __builtin_amdgcn_mfma_f32_16x16x32_bf16(a, bfr, cinit, 0, 0, 0);
        if (j != il) {                  // drop self-edge, shift rows after it
            const int jj = j - (j > il);
            f32x4* dst = reinterpret_cast<f32x4*>(outb + (size_t)jj * 16 + q * 4);
            __builtin_nontemporal_store(acc, dst);   // 268 MB stream: evict-first
        }
    }
}

extern "C" void kernel_launch(void* const* d_in, const int* in_sizes, int n_in,
                              void* d_out, int out_size, void* d_ws, size_t ws_size,
                              hipStream_t stream)
{
    const float* nodes = (const float*)d_in[0];
    const float* W_bil = (const float*)d_in[1];
    const float* b_bil = (const float*)d_in[2];
    const float* W2    = (const float*)d_in[3];
    const float* b2    = (const float*)d_in[4];
    const float* W3    = (const float*)d_in[5];
    const float* b3    = (const float*)d_in[6];
    // d_in[7] = num_batches (device scalar); derive B host-side instead:
    // out_size/16 = B*M*(M-1) = N*(M-1)  =>  M = out_size/(16N) + 1
    const int N = in_sizes[0] / 16;
    const int M = out_size / (16 * N) + 1;

    char* ws = (char*)d_ws;
    float*          Weff = (float*)(ws);
    float*          beff = (float*)(ws + 16384);
    __hip_bfloat16* Xb   = (__hip_bfloat16*)(ws + 16448);
    float* out = (float*)d_out;

    k_prep<<<16, 256, 0, stream>>>(nodes, W_bil, b_bil, W2, b2, W3, b3,
                                   Weff, beff, Xb, N);
    k_main<<<N, 256, 0, stream>>>(nodes, Weff, Xb, beff, out, M);  // grid = B*M = N
}

// Round 2
// 275.694 us; speedup vs baseline: 1.0513x; 1.0513x over previous
//
#include <hip/hip_runtime.h>
#include <hip/hip_bf16.h>

typedef __attribute__((ext_vector_type(8))) short short8;  // 8 bf16 (4 VGPRs)
typedef __attribute__((ext_vector_type(4))) float f32x4;   // MFMA acc

// ws layout (bytes):
//   [0,     16384)             Weff fp32 [16][16][16]  (p,d,e)
//   [16384, 16448)             beff fp32 [16]
//   [16448, 16448 + N*64)      Xb  bf16 [N][32]      (e padded 16->32, zeros)
//   [...,   ... + N*1024)      U   bf16 [N][16][32]  (p, e padded, zeros)
// All sub-offsets 16B-aligned for dwordx4 access.

__global__ void k_prep(const float* __restrict__ nodes,
                       const float* __restrict__ W_bil,
                       const float* __restrict__ b_bil,
                       const float* __restrict__ W2,
                       const float* __restrict__ b2,
                       const float* __restrict__ W3,
                       const float* __restrict__ b3,
                       float* __restrict__ Weff,
                       float* __restrict__ beff,
                       __hip_bfloat16* __restrict__ Xb,
                       int N)
{
    const int p = blockIdx.x;   // 16 blocks, one output channel each
    const int t = threadIdx.x;  // 256 threads

    __shared__ float wc[16];    // Wc[p][k] = sum_o W3[p,o] W2[o,k]
    if (t < 16) {
        float s = 0.f;
        #pragma unroll
        for (int o = 0; o < 16; ++o) s += W3[p * 16 + o] * W2[o * 16 + t];
        wc[t] = s;
    }
    __syncthreads();

    {   // Weff[p][d][e] = sum_k Wc[p,k] * W_bil[k,d,e]
        const int d = t >> 4, e = t & 15;
        float s = 0.f;
        #pragma unroll
        for (int k = 0; k < 16; ++k) s += wc[k] * W_bil[(k * 16 + d) * 16 + e];
        Weff[(p * 16 + d) * 16 + e] = s;
    }

    if (p == 0 && t < 16) {  // beff[t] = Wc[t,:]@b_bil + W3[t,:]@b2 + b3[t]
        float acc = b3[t];
        #pragma unroll
        for (int o = 0; o < 16; ++o) acc += W3[t * 16 + o] * b2[o];
        #pragma unroll
        for (int k = 0; k < 16; ++k) {
            float wck = 0.f;
            #pragma unroll
            for (int o = 0; o < 16; ++o) wck += W3[t * 16 + o] * W2[o * 16 + k];
            acc += wck * b_bil[k];
        }
        beff[t] = acc;
    }

    {   // Xb: one node row per thread (16 blocks * 256 = N), K-padded to 32
        const int n = p * 256 + t;
        if (n < N) {
            const float* src = nodes + (size_t)n * 16;
            __hip_bfloat16* dst = Xb + (size_t)n * 32;
            #pragma unroll
            for (int e = 0; e < 16; ++e) dst[e] = __float2bfloat16(src[e]);
            #pragma unroll
            for (int e = 16; e < 32; ++e) dst[e] = __float2bfloat16(0.f);
        }
    }
}

// U[i][p][e] = sum_d x[i,d] * Weff[p,d,e], stored bf16 with e padded to 32.
__global__ void k_u(const float* __restrict__ nodes,
                    const float* __restrict__ Weff,
                    __hip_bfloat16* __restrict__ U)
{
    const int i = blockIdx.x;     // one node row per block
    const int t = threadIdx.x;    // 256 = 16p x 16e

    __shared__ float xr[16];
    if (t < 16) xr[t] = nodes[(size_t)i * 16 + t];
    __syncthreads();

    const int p = t >> 4, e = t & 15;
    float s = 0.f;
    #pragma unroll
    for (int d = 0; d < 16; ++d) s += xr[d] * Weff[(p * 16 + d) * 16 + e];

    __hip_bfloat16* row = U + (size_t)i * 512;   // 16*32
    row[p * 32 + e]      = __float2bfloat16(s);
    row[p * 32 + 16 + e] = __float2bfloat16(0.f);  // K zero-pad
}

// Wave-persistent main: each WAVE owns one node i and processes all 64 j-tiles
// in a single uninterrupted run: 16B A-frag load, then 64x {load B, MFMA, store}.
// No LDS, no barriers, no inter-wave coupling. Each wave writes a contiguous
// 64KB output region -> store duty cycle stays high (the fill kernel saturates
// HBM writes at ~3 waves/CU; we have 16 waves/CU with long store bursts).
// C/D layout (m89-verified): col = lane&15 (=j), row = (lane>>4)*4 + reg (=p)
// -> each lane's 4 accs are 4 consecutive channels of one output row: 16B store.
__global__ __launch_bounds__(256) void k_main(
    const __hip_bfloat16* __restrict__ U,    // [N][16][32] bf16
    const __hip_bfloat16* __restrict__ Xb,   // [N][32] bf16
    const float* __restrict__ beff,          // [16]
    float* __restrict__ out,                 // [B*M*(M-1)][16] fp32
    int M)
{
    const int t    = threadIdx.x;
    const int w    = t >> 6;            // wave 0..3
    const int lane = t & 63;
    const int q    = lane >> 4;         // quad
    const int r16  = lane & 15;

    const int blk = blockIdx.x * 4 + w; // global node index i (one per wave)
    const int il  = blk % M;
    const int bM  = blk - il;           // b*M

    // A-frag: A[m=lane&15][k=quad*8+j] = U[i][p=r16][e=q*8..+7] (contiguous 16B)
    const unsigned short* Uu = reinterpret_cast<const unsigned short*>(U);
    const short8 a = *reinterpret_cast<const short8*>(
        Uu + (size_t)blk * 512 + r16 * 32 + q * 8);

    // Acc init with beff: lane reg r holds D[p=q*4+r][*]
    f32x4 cinit;
    {
        const float4 bv = *reinterpret_cast<const float4*>(beff + q * 4);
        cinit = f32x4{bv.x, bv.y, bv.z, bv.w};
    }

    const unsigned short* Xu = reinterpret_cast<const unsigned short*>(Xb);
    const size_t xbase = (size_t)bM * 32;
    float* outb = out + (size_t)blk * (M - 1) * 16;

    const int ntiles = M >> 4;          // 64
    #pragma unroll 4
    for (int jt = 0; jt < ntiles; ++jt) {
        const int j = jt * 16 + r16;    // this lane's output column (node j)
        // B-frag: B[k=quad*8+i][n=lane&15] = Xb[bM+j][e=q*8..+7]
        const short8 bfr = *reinterpret_cast<const short8*>(
            Xu + xbase + (size_t)j * 32 + q * 8);
        const f32x4 acc = __builtin_amdgcn_mfma_f32_16x16x32_bf16(a, bfr, cinit, 0, 0, 0);
        if (j != il) {                  // drop self-edge, shift rows after it
            const int jj = j - (j > il);
            f32x4* dst = reinterpret_cast<f32x4*>(outb + (size_t)jj * 16 + q * 4);
            *dst = acc;
        }
    }
}

extern "C" void kernel_launch(void* const* d_in, const int* in_sizes, int n_in,
                              void* d_out, int out_size, void* d_ws, size_t ws_size,
                              hipStream_t stream)
{
    const float* nodes = (const float*)d_in[0];
    const float* W_bil = (const float*)d_in[1];
    const float* b_bil = (const float*)d_in[2];
    const float* W2    = (const float*)d_in[3];
    const float* b2    = (const float*)d_in[4];
    const float* W3    = (const float*)d_in[5];
    const float* b3    = (const float*)d_in[6];
    // d_in[7] = num_batches (device scalar); derive B host-side instead:
    // out_size/16 = B*M*(M-1) = N*(M-1)  =>  M = out_size/(16N) + 1
    const int N = in_sizes[0] / 16;
    const int M = out_size / (16 * N) + 1;

    char* ws = (char*)d_ws;
    float*          Weff = (float*)(ws);
    float*          beff = (float*)(ws + 16384);
    __hip_bfloat16* Xb   = (__hip_bfloat16*)(ws + 16448);
    __hip_bfloat16* U    = (__hip_bfloat16*)(ws + 16448 + (size_t)N * 64);
    float* out = (float*)d_out;

    k_prep<<<16, 256, 0, stream>>>(nodes, W_bil, b_bil, W2, b2, W3, b3,
                                   Weff, beff, Xb, N);
    k_u<<<N, 256, 0, stream>>>(nodes, Weff, U);
    k_main<<<N / 4, 256, 0, stream>>>(U, Xb, beff, out, M);  // 1 wave per node i
}